// Round 1
// 591.988 us; speedup vs baseline: 1.0865x; 1.0865x over previous
//
#include <hip/hip_runtime.h>

typedef float    f32x4 __attribute__((ext_vector_type(4)));
typedef _Float16 f16x4 __attribute__((ext_vector_type(4)));
typedef _Float16 f16x8 __attribute__((ext_vector_type(8)));

// direct global->LDS DMA, 16B per lane. LDS dest must be wave-uniform;
// HW writes lane l at (ldsbase + l*16).
__device__ __forceinline__ void gload16(const _Float16* g, _Float16* l) {
  __builtin_amdgcn_global_load_lds(
      (__attribute__((address_space(1))) void*)g,
      (__attribute__((address_space(3))) void*)l, 16, 0, 0);
}

// ---------------------------------------------------------------------------
// Unified 128x128 all-fp16 GEMM, C = A * B^T (+bias), fp32 accum,
// 16x16x32 f16 MFMA, BK=32, m97 structure:
//   global_load_lds width=16 into unpadded [128][32]-half tiles (64B rows;
//   bank-balanced in aggregate for both the DMA writes and ds_read_b128),
//   one stage + 2 barriers per K-step. Measured ladder: this staging path
//   is the 546->911 TF lever (global_load_lds vs manual VGPR round-trip).
// A: [M,K], B: [N,K] row-major fp16. K % 32 == 0, M,N % 128 == 0.
// ---------------------------------------------------------------------------
template <typename TOUT, bool BIAS>
__global__ __launch_bounds__(256) void gemm128h(
    const _Float16* __restrict__ A, const _Float16* __restrict__ B,
    const float* __restrict__ bias, TOUT* __restrict__ Cp,
    int M, int N, int K, long sA, long sB, long sC) {
  __shared__ _Float16 As[128 * 32];
  __shared__ _Float16 Bs[128 * 32];
  const int tid = threadIdx.x;
  const int lane = tid & 63, wv = tid >> 6;
  const int wr = (wv >> 1) * 64, wc = (wv & 1) * 64;
  const int l15 = lane & 15, k8 = (lane >> 4) * 8;
  const int m0 = blockIdx.y * 128, n0 = blockIdx.x * 128;
  const _Float16* Ab = A + (size_t)blockIdx.z * sA;
  const _Float16* Bb = B + (size_t)blockIdx.z * sB;

  // staging geometry: wave chunk t = wv*2+r covers rows [t*16, t*16+16),
  // lane l -> row t*16 + (l>>2), half-col (l&3)*8  (matches base + l*16B)
  const int srow = lane >> 2;
  const int sc8  = (lane & 3) * 8;

  f32x4 acc[4][4] = {};

  for (int k0 = 0; k0 < K; k0 += 32) {
    #pragma unroll
    for (int r = 0; r < 2; r++) {
      const int t = wv * 2 + r;
      const int row = t * 16 + srow;
      gload16(&Ab[(size_t)(m0 + row) * K + k0 + sc8], &As[t * 512]);
      gload16(&Bb[(size_t)(n0 + row) * K + k0 + sc8], &Bs[t * 512]);
    }
    __syncthreads();   // compiler drains vmcnt(0) here -> LDS tiles ready
    f16x8 af[4], bf[4];
    #pragma unroll
    for (int i = 0; i < 4; i++)
      af[i] = *(const f16x8*)&As[(wr + i * 16 + l15) * 32 + k8];
    #pragma unroll
    for (int j = 0; j < 4; j++)
      bf[j] = *(const f16x8*)&Bs[(wc + j * 16 + l15) * 32 + k8];
    #pragma unroll
    for (int i = 0; i < 4; i++)
      #pragma unroll
      for (int j = 0; j < 4; j++)
        acc[i][j] = __builtin_amdgcn_mfma_f32_16x16x32_f16(af[i], bf[j],
                                                           acc[i][j], 0, 0, 0);
    __syncthreads();
  }

  TOUT* C = Cp + (size_t)blockIdx.z * sC;
  const int q4 = (lane >> 4) * 4;
  #pragma unroll
  for (int j = 0; j < 4; j++) {
    int col = n0 + wc + j * 16 + l15;
    float bb = BIAS ? bias[col] : 0.0f;
    #pragma unroll
    for (int i = 0; i < 4; i++) {
      int rowb = m0 + wr + i * 16 + q4;
      #pragma unroll
      for (int rr = 0; rr < 4; rr++)
        C[(size_t)(rowb + rr) * N + col] = (TOUT)(acc[i][j][rr] + bb);
    }
  }
}

// ---------------------------------------------------------------------------
// fp16 transpose: dst[b][d][m] = src[b][m][d].  64x64 tiles, [64][64]-half
// LDS with XOR swizzle on 8-half groups (group ^= (row>>3)&7) -> both the
// f16x8 writes and the per-half column gathers are bank-conflict-free.
// ---------------------------------------------------------------------------
__global__ __launch_bounds__(256) void transpose16_kernel(
    const _Float16* __restrict__ src, _Float16* __restrict__ dst) {
  const int Lm = 2048, D = 1024;
  __shared__ _Float16 tile[64 * 64];
  const int d0 = blockIdx.x * 64, m0 = blockIdx.y * 64;
  const _Float16* s = src + (size_t)blockIdx.z * Lm * D;
  _Float16*       d = dst + (size_t)blockIdx.z * D * Lm;
  const int tid = threadIdx.x;
  #pragma unroll
  for (int it = 0; it < 2; it++) {
    int idx = tid + it * 256;
    int mm = idx >> 3, g = idx & 7;                 // row, 8-half group
    int pg = g ^ ((mm >> 3) & 7);                   // swizzled group
    *(f16x8*)&tile[mm * 64 + pg * 8] =
        *(const f16x8*)&s[(size_t)(m0 + mm) * D + d0 + g * 8];
  }
  __syncthreads();
  #pragma unroll
  for (int it = 0; it < 2; it++) {
    int idx = tid + it * 256;
    int dd = idx >> 3, mc = (idx & 7) * 8;
    f16x8 h;
    #pragma unroll
    for (int j = 0; j < 8; j++) {
      int row = mc + j;
      int pg = (dd >> 3) ^ ((row >> 3) & 7);
      h[j] = tile[row * 64 + pg * 8 + (dd & 7)];
    }
    *(f16x8*)&d[(size_t)(d0 + dd) * Lm + m0 + mc] = h;
  }
}

// ---------------------------------------------------------------------------
// per-row mask + softmax in place over fp16 logits; one block per (b,q) row
// ---------------------------------------------------------------------------
__global__ __launch_bounds__(256) void softmax_kernel(
    const int* __restrict__ mask, _Float16* __restrict__ wbuf) {
  const int Lm = 2048;
  size_t row = blockIdx.x;
  _Float16* wr = wbuf + row * Lm;
  const int* mr = mask + row * Lm;
  int tid = threadIdx.x;
  f16x8 lv = *(const f16x8*)&wr[tid * 8];
  int4 ma = *(const int4*)&mr[tid * 8];
  int4 mb = *(const int4*)&mr[tid * 8 + 4];
  int mk[8] = {ma.x, ma.y, ma.z, ma.w, mb.x, mb.y, mb.z, mb.w};
  float v[8];
  float mx = -3.0e38f;
  #pragma unroll
  for (int i = 0; i < 8; i++) {
    float l = (float)lv[i];
    if (mk[i] == 0) l += -1000000.0f;
    v[i] = l;
    mx = fmaxf(mx, l);
  }
  #pragma unroll
  for (int off = 32; off > 0; off >>= 1) mx = fmaxf(mx, __shfl_down(mx, off, 64));
  __shared__ float red[4];
  int wv = tid >> 6;
  if ((tid & 63) == 0) red[wv] = mx;
  __syncthreads();
  mx = fmaxf(fmaxf(red[0], red[1]), fmaxf(red[2], red[3]));
  __syncthreads();
  float s = 0.f;
  #pragma unroll
  for (int i = 0; i < 8; i++) { v[i] = __expf(v[i] - mx); s += v[i]; }
  #pragma unroll
  for (int off = 32; off > 0; off >>= 1) s += __shfl_down(s, off, 64);
  if ((tid & 63) == 0) red[wv] = s;
  __syncthreads();
  float inv = 1.0f / (red[0] + red[1] + red[2] + red[3]);
  f16x8 o;
  #pragma unroll
  for (int i = 0; i < 8; i++) o[i] = (_Float16)(v[i] * inv);
  *(f16x8*)&wr[tid * 8] = o;
}

// ---------------------------------------------------------------------------
// fp32 -> fp16 convert, 8 elems/thread (f32x4 x2 -> f16x8 16B store)
// ---------------------------------------------------------------------------
__global__ __launch_bounds__(256) void cvt8_kernel(const float* __restrict__ x,
                                                   _Float16* __restrict__ y) {
  size_t i = (size_t)(blockIdx.x * 256 + threadIdx.x) * 8;
  f32x4 a = *(const f32x4*)&x[i];
  f32x4 b = *(const f32x4*)&x[i + 4];
  f16x8 h = {(_Float16)a[0], (_Float16)a[1], (_Float16)a[2], (_Float16)a[3],
             (_Float16)b[0], (_Float16)b[1], (_Float16)b[2], (_Float16)b[3]};
  *(f16x8*)&y[i] = h;
}

// ---------------------------------------------------------------------------
// B=8, Lq=Lm=2048, Din=Dout=1024
//
// All GEMMs are now pure-fp16 so every operand stages via global_load_lds
// (the fp32->fp16 cvts are hoisted into cheap memory-bound pre-passes).
//
// buffer plan (ws = 96 MB, d_out = 64 MB used as scratch before pv):
//   ws[0,32M):   qproj fp16 [16384,1024]   (proj -> scores);
//                then memT fp16 [B,1024,2048] overwrites it (after scores)
//   ws[32M,64M): queryh fp16 (transient, dead after proj)
//   ws[64M,66M): Wh fp16     (transient, dead after proj)
//   ws[32M,96M): wbuf fp16 [B,Lq,Lm] (scores -> softmax in place -> pv)
//   d_out[0,32M): memh fp16 [B,2048,1024] (cvt of mem; read by scores and
//                the transpose; dead before pv writes out)
//
// BUGFIX (kept from prior session): pv's output batch stride is LQK
// (out is [B,2048,1024]), NOT LQM.
// ---------------------------------------------------------------------------
extern "C" void kernel_launch(void* const* d_in, const int* in_sizes, int n_in,
                              void* d_out, int out_size, void* d_ws, size_t ws_size,
                              hipStream_t stream) {
  const float* query = (const float*)d_in[0];
  const float* mem   = (const float*)d_in[1];
  const int*   mask  = (const int*)d_in[2];
  const float* W     = (const float*)d_in[3];
  const float* bias  = (const float*)d_in[4];
  float* out = (float*)d_out;

  char* ws = (char*)d_ws;
  _Float16* qproj  = (_Float16*)ws;                                // 32 MB
  _Float16* memT   = (_Float16*)ws;                                // aliases qproj
  _Float16* queryh = (_Float16*)(ws + (size_t)32 * 1024 * 1024);   // transient
  _Float16* Wh     = (_Float16*)(ws + (size_t)64 * 1024 * 1024);   // transient
  _Float16* wbuf   = (_Float16*)(ws + (size_t)32 * 1024 * 1024);   // 64 MB
  _Float16* memh   = (_Float16*)d_out;                             // 32 MB scratch

  const long LQK = 2048L * 1024, LQM = 2048L * 2048;

  // fp32 -> fp16 pre-passes
  cvt8_kernel<<<dim3(512),  256, 0, stream>>>(W, Wh);        // 1M elems
  cvt8_kernel<<<dim3(8192), 256, 0, stream>>>(query, queryh);// 16.8M elems
  cvt8_kernel<<<dim3(8192), 256, 0, stream>>>(mem, memh);    // 16.8M elems
  // proj: qproj[16384,1024] = queryh * Wh^T + b
  gemm128h<_Float16, true><<<dim3(8, 128, 1), 256, 0, stream>>>(
      queryh, Wh, bias, qproj, 16384, 1024, 1024, 0, 0, 0);
  // scores: wbuf[b][2048,2048] = qproj * memh^T   (overwrites queryh/Wh, dead)
  gemm128h<_Float16, false><<<dim3(16, 16, 8), 256, 0, stream>>>(
      qproj, memh, nullptr, wbuf, 2048, 2048, 1024, LQK, LQK, LQM);
  // mask + softmax in place
  softmax_kernel<<<dim3(16384), 256, 0, stream>>>(mask, wbuf);
  // memT[b][1024,2048] = memh^T   (qproj dead -> reuse its space)
  transpose16_kernel<<<dim3(16, 32, 8), 256, 0, stream>>>(memh, memT);
  // pv: out[b][2048,1024] = wbuf * memT^T   (sC = LQK, NOT LQM!)
  gemm128h<float, false><<<dim3(8, 16, 8), 256, 0, stream>>>(
      wbuf, memT, nullptr, out, 2048, 1024, 2048, LQM, LQK, LQK);
}

// Round 2
// 514.156 us; speedup vs baseline: 1.2509x; 1.1514x over previous
//
#include <hip/hip_runtime.h>

typedef float    f32x4 __attribute__((ext_vector_type(4)));
typedef _Float16 f16x4 __attribute__((ext_vector_type(4)));
typedef _Float16 f16x8 __attribute__((ext_vector_type(8)));

// direct global->LDS DMA, 16B per lane. LDS dest is wave-uniform base;
// HW writes lane l at (ldsbase + l*16). Global src is per-lane.
__device__ __forceinline__ void gload16(const void* g, void* l) {
  __builtin_amdgcn_global_load_lds(
      (const __attribute__((address_space(1))) void*)g,
      (__attribute__((address_space(3))) void*)l, 16, 0, 0);
}

#define MFMA16(d, a, b) __builtin_amdgcn_mfma_f32_16x16x32_f16(a, b, d, 0, 0, 0)

// ---------------------------------------------------------------------------
// 256x256 deep-pipelined fp16 GEMM, C = A * B^T (+bias), fp32 accum.
// 512 thr = 8 waves (2M x 4N), per-wave C = 128x64, acc[8][4] f32x4.
// BK=64 split as 2 K-halves of 32; LDS = 2 dbuf x {A,B} x 2 K-half x 16KB
// = 128 KiB.  Layout per K-half: [256 rows][32 halfs] (64B rows), XOR
// swizzle cb ^= ((row>>2)&3)<<4 applied via pre-swizzled GLOBAL source
// (linear DMA dest) + swizzled ds_read addr (rule #21).  Reads are 2-way
// bank-aliased = free (m136).
//
// Schedule per K-tile t (buf d=t&1, staging tile t+1 into d^1):
//   p0 (kk0,qn0): ds_read af[8]+bf[2] | stage A-K0(t+1) | bar | 16 MFMA | bar
//   p1 (kk0,qn1): ds_read bf[2]       | stage B-K0(t+1) | vmcnt(4) bar | MFMA | bar
//   p2 (kk1,qn0): ds_read af[8]+bf[2] | stage A-K1(t+1) | bar | MFMA | bar
//   p3 (kk1,qn1): ds_read bf[2]       | stage B-K1(t+1) | vmcnt(4) bar | MFMA | bar
// vmcnt(4) derivation: the 4 allowed outstanding loads are exactly the two
// not-yet-read half-tiles; everything older (the half about to be ds_read)
// is forced landed, and the following s_barrier publishes that guarantee
// across waves.  Loads never drain to 0 in the main loop (T4).
// ---------------------------------------------------------------------------
template <bool STG>
__device__ __forceinline__ void ktile256(
    char* L, int d, size_t go,
    const char* aSrc0, const char* aSrc1,
    const char* bSrc0, const char* bSrc1,
    int ldsStage, int wr, int wc, int l15, int rcb,
    f32x4 (&acc)[8][4]) {
  const char* Ab0 = L + d * 32768;
  const char* Bb0 = L + 65536 + d * 32768;
  const int dn = d ^ 1;
  f16x8 af[8], bf[2];

  // ---- phase 0: kk=0, qn=0 ----
  #pragma unroll
  for (int m = 0; m < 8; m++)
    af[m] = *(const f16x8*)(Ab0 + (wr + m * 16 + l15) * 64 + rcb);
  #pragma unroll
  for (int n = 0; n < 2; n++)
    bf[n] = *(const f16x8*)(Bb0 + (wc + n * 16 + l15) * 64 + rcb);
  if constexpr (STG) {
    char* dst = L + dn * 32768 + ldsStage;          // A-K0 of t+1
    gload16(aSrc0 + go, dst);
    gload16(aSrc1 + go, dst + 1024);
  }
  __builtin_amdgcn_s_barrier();
  __builtin_amdgcn_s_setprio(1);
  #pragma unroll
  for (int m = 0; m < 8; m++) {
    acc[m][0] = MFMA16(acc[m][0], af[m], bf[0]);
    acc[m][1] = MFMA16(acc[m][1], af[m], bf[1]);
  }
  __builtin_amdgcn_s_setprio(0);
  __builtin_amdgcn_s_barrier();

  // ---- phase 1: kk=0, qn=1 (reuse af) ----
  #pragma unroll
  for (int n = 0; n < 2; n++)
    bf[n] = *(const f16x8*)(Bb0 + (wc + (2 + n) * 16 + l15) * 64 + rcb);
  if constexpr (STG) {
    char* dst = L + 65536 + dn * 32768 + ldsStage;  // B-K0 of t+1
    gload16(bSrc0 + go, dst);
    gload16(bSrc1 + go, dst + 1024);
    asm volatile("s_waitcnt vmcnt(4)" ::: "memory"); // force this tile's K1 landed
  } else {
    asm volatile("s_waitcnt vmcnt(0)" ::: "memory"); // last tile: drain
  }
  __builtin_amdgcn_s_barrier();
  __builtin_amdgcn_s_setprio(1);
  #pragma unroll
  for (int m = 0; m < 8; m++) {
    acc[m][2] = MFMA16(acc[m][2], af[m], bf[0]);
    acc[m][3] = MFMA16(acc[m][3], af[m], bf[1]);
  }
  __builtin_amdgcn_s_setprio(0);
  __builtin_amdgcn_s_barrier();

  // ---- phase 2: kk=1, qn=0 ----
  #pragma unroll
  for (int m = 0; m < 8; m++)
    af[m] = *(const f16x8*)(Ab0 + 16384 + (wr + m * 16 + l15) * 64 + rcb);
  #pragma unroll
  for (int n = 0; n < 2; n++)
    bf[n] = *(const f16x8*)(Bb0 + 16384 + (wc + n * 16 + l15) * 64 + rcb);
  if constexpr (STG) {
    char* dst = L + dn * 32768 + 16384 + ldsStage;  // A-K1 of t+1
    gload16(aSrc0 + go + 64, dst);
    gload16(aSrc1 + go + 64, dst + 1024);
  }
  __builtin_amdgcn_s_barrier();
  __builtin_amdgcn_s_setprio(1);
  #pragma unroll
  for (int m = 0; m < 8; m++) {
    acc[m][0] = MFMA16(acc[m][0], af[m], bf[0]);
    acc[m][1] = MFMA16(acc[m][1], af[m], bf[1]);
  }
  __builtin_amdgcn_s_setprio(0);
  __builtin_amdgcn_s_barrier();

  // ---- phase 3: kk=1, qn=1 ----
  #pragma unroll
  for (int n = 0; n < 2; n++)
    bf[n] = *(const f16x8*)(Bb0 + 16384 + (wc + (2 + n) * 16 + l15) * 64 + rcb);
  if constexpr (STG) {
    char* dst = L + 65536 + dn * 32768 + 16384 + ldsStage;  // B-K1 of t+1
    gload16(bSrc0 + go + 64, dst);
    gload16(bSrc1 + go + 64, dst + 1024);
    asm volatile("s_waitcnt vmcnt(4)" ::: "memory"); // force next tile's K0 landed
  }
  __builtin_amdgcn_s_barrier();
  __builtin_amdgcn_s_setprio(1);
  #pragma unroll
  for (int m = 0; m < 8; m++) {
    acc[m][2] = MFMA16(acc[m][2], af[m], bf[0]);
    acc[m][3] = MFMA16(acc[m][3], af[m], bf[1]);
  }
  __builtin_amdgcn_s_setprio(0);
  __builtin_amdgcn_s_barrier();
}

template <typename TOUT, bool BIAS>
__global__ __launch_bounds__(512) void gemm256(
    const _Float16* __restrict__ A, const _Float16* __restrict__ B,
    const float* __restrict__ bias, TOUT* __restrict__ Cp,
    int M, int N, int K, long sA, long sB, long sC) {
  __shared__ _Float16 lds[65536];   // 128 KB: A[2][2][256][32] | B[2][2][256][32]
  char* const L = (char*)lds;
  const int tid = threadIdx.x;
  const int w = tid >> 6, l = tid & 63;
  const int l15 = l & 15, q = l >> 4;
  const int wr = (w >> 2) * 128, wc = (w & 3) * 64;
  const int m0 = blockIdx.y * 256, n0 = blockIdx.x * 256;
  const _Float16* Ab = A + (size_t)blockIdx.z * sA;
  const _Float16* Bb = B + (size_t)blockIdx.z * sB;

  // stage addressing: thread covers stored bytes X=(w*2+r)*1024+l*16 of a
  // 16KB K-half; row=X>>6, stored col=X&63, logical col = stored ^ swz(row).
  // Simplifies to lane-constant scb and rows {sr0, sr0+16}.
  const int scb = ((l & 3) ^ q) << 4;
  const int sr0 = w * 32 + (l >> 2);
  const char* aSrc0 = (const char*)(Ab + (size_t)(m0 + sr0) * K) + scb;
  const char* aSrc1 = (const char*)(Ab + (size_t)(m0 + sr0 + 16) * K) + scb;
  const char* bSrc0 = (const char*)(Bb + (size_t)(n0 + sr0) * K) + scb;
  const char* bSrc1 = (const char*)(Bb + (size_t)(n0 + sr0 + 16) * K) + scb;
  const int ldsStage = w * 2048;              // wave's 2KB within a 16KB half
  const int rcb = ((q ^ (l15 >> 2)) << 4);    // swizzled read col (lane-const)

  f32x4 acc[8][4] = {};
  const int NT = K >> 6;

  // prologue: stage tile 0 (A-K0, B-K0, A-K1, B-K1) into buf 0
  {
    char* dA = L + ldsStage;
    char* dB = L + 65536 + ldsStage;
    gload16(aSrc0, dA);       gload16(aSrc1, dA + 1024);
    gload16(bSrc0, dB);       gload16(bSrc1, dB + 1024);
    gload16(aSrc0 + 64, dA + 16384); gload16(aSrc1 + 64, dA + 16384 + 1024);
    gload16(bSrc0 + 64, dB + 16384); gload16(bSrc1 + 64, dB + 16384 + 1024);
    asm volatile("s_waitcnt vmcnt(4)" ::: "memory");  // K0 landed, K1 in flight
  }
  __builtin_amdgcn_s_barrier();

  for (int t = 0; t < NT - 1; ++t)
    ktile256<true>(L, t & 1, (size_t)(t + 1) * 128, aSrc0, aSrc1, bSrc0, bSrc1,
                   ldsStage, wr, wc, l15, rcb, acc);
  ktile256<false>(L, (NT - 1) & 1, 0, aSrc0, aSrc1, bSrc0, bSrc1,
                  ldsStage, wr, wc, l15, rcb, acc);

  TOUT* C = Cp + (size_t)blockIdx.z * sC;
  const int q4 = q * 4;
  #pragma unroll
  for (int n = 0; n < 4; n++) {
    int col = n0 + wc + n * 16 + l15;
    float bb = BIAS ? bias[col] : 0.0f;
    #pragma unroll
    for (int m = 0; m < 8; m++) {
      int rowb = m0 + wr + m * 16 + q4;
      #pragma unroll
      for (int rr = 0; rr < 4; rr++)
        C[(size_t)(rowb + rr) * N + col] = (TOUT)(acc[m][n][rr] + bb);
    }
  }
}

// ---------------------------------------------------------------------------
// fp16 transpose: dst[b][d][m] = src[b][m][d].  64x64 tiles, XOR-swizzled
// 8-half groups -> conflict-free both sides.
// ---------------------------------------------------------------------------
__global__ __launch_bounds__(256) void transpose16_kernel(
    const _Float16* __restrict__ src, _Float16* __restrict__ dst) {
  const int Lm = 2048, D = 1024;
  __shared__ _Float16 tile[64 * 64];
  const int d0 = blockIdx.x * 64, m0 = blockIdx.y * 64;
  const _Float16* s = src + (size_t)blockIdx.z * Lm * D;
  _Float16*       d = dst + (size_t)blockIdx.z * D * Lm;
  const int tid = threadIdx.x;
  #pragma unroll
  for (int it = 0; it < 2; it++) {
    int idx = tid + it * 256;
    int mm = idx >> 3, g = idx & 7;
    int pg = g ^ ((mm >> 3) & 7);
    *(f16x8*)&tile[mm * 64 + pg * 8] =
        *(const f16x8*)&s[(size_t)(m0 + mm) * D + d0 + g * 8];
  }
  __syncthreads();
  #pragma unroll
  for (int it = 0; it < 2; it++) {
    int idx = tid + it * 256;
    int dd = idx >> 3, mc = (idx & 7) * 8;
    f16x8 h;
    #pragma unroll
    for (int j = 0; j < 8; j++) {
      int row = mc + j;
      int pg = (dd >> 3) ^ ((row >> 3) & 7);
      h[j] = tile[row * 64 + pg * 8 + (dd & 7)];
    }
    *(f16x8*)&d[(size_t)(d0 + dd) * Lm + m0 + mc] = h;
  }
}

// ---------------------------------------------------------------------------
// per-row mask + softmax in place over fp16 logits; one block per (b,q) row
// ---------------------------------------------------------------------------
__global__ __launch_bounds__(256) void softmax_kernel(
    const int* __restrict__ mask, _Float16* __restrict__ wbuf) {
  const int Lm = 2048;
  size_t row = blockIdx.x;
  _Float16* wr = wbuf + row * Lm;
  const int* mr = mask + row * Lm;
  int tid = threadIdx.x;
  f16x8 lv = *(const f16x8*)&wr[tid * 8];
  int4 ma = *(const int4*)&mr[tid * 8];
  int4 mb = *(const int4*)&mr[tid * 8 + 4];
  int mk[8] = {ma.x, ma.y, ma.z, ma.w, mb.x, mb.y, mb.z, mb.w};
  float v[8];
  float mx = -3.0e38f;
  #pragma unroll
  for (int i = 0; i < 8; i++) {
    float l = (float)lv[i];
    if (mk[i] == 0) l += -1000000.0f;
    v[i] = l;
    mx = fmaxf(mx, l);
  }
  #pragma unroll
  for (int off = 32; off > 0; off >>= 1) mx = fmaxf(mx, __shfl_down(mx, off, 64));
  __shared__ float red[4];
  int wv = tid >> 6;
  if ((tid & 63) == 0) red[wv] = mx;
  __syncthreads();
  mx = fmaxf(fmaxf(red[0], red[1]), fmaxf(red[2], red[3]));
  __syncthreads();
  float s = 0.f;
  #pragma unroll
  for (int i = 0; i < 8; i++) { v[i] = __expf(v[i] - mx); s += v[i]; }
  #pragma unroll
  for (int off = 32; off > 0; off >>= 1) s += __shfl_down(s, off, 64);
  if ((tid & 63) == 0) red[wv] = s;
  __syncthreads();
  float inv = 1.0f / (red[0] + red[1] + red[2] + red[3]);
  f16x8 o;
  #pragma unroll
  for (int i = 0; i < 8; i++) o[i] = (_Float16)(v[i] * inv);
  *(f16x8*)&wr[tid * 8] = o;
}

// ---------------------------------------------------------------------------
// fp32 -> fp16 convert, 8 elems/thread
// ---------------------------------------------------------------------------
__global__ __launch_bounds__(256) void cvt8_kernel(const float* __restrict__ x,
                                                   _Float16* __restrict__ y) {
  size_t i = (size_t)(blockIdx.x * 256 + threadIdx.x) * 8;
  f32x4 a = *(const f32x4*)&x[i];
  f32x4 b = *(const f32x4*)&x[i + 4];
  f16x8 h = {(_Float16)a[0], (_Float16)a[1], (_Float16)a[2], (_Float16)a[3],
             (_Float16)b[0], (_Float16)b[1], (_Float16)b[2], (_Float16)b[3]};
  *(f16x8*)&y[i] = h;
}

// ---------------------------------------------------------------------------
// B=8, Lq=Lm=2048, Din=Dout=1024
//
// buffer plan (ws = 96 MB, d_out = 64 MB used as scratch before pv):
//   ws[0,32M):   qproj fp16 [16384,1024] (proj -> scores);
//                then memT fp16 [B,1024,2048] overwrites it (after scores)
//   ws[32M,64M): queryh fp16 (transient, dead after proj)
//   ws[64M,66M): Wh fp16     (transient, dead after proj)
//   ws[32M,96M): wbuf fp16 [B,Lq,Lm] (scores -> softmax in place -> pv)
//   d_out[0,32M): memh fp16 (cvt of mem; dead before pv writes out)
//
// BUGFIX (kept): pv's output batch stride is LQK (out is [B,2048,1024]).
// ---------------------------------------------------------------------------
extern "C" void kernel_launch(void* const* d_in, const int* in_sizes, int n_in,
                              void* d_out, int out_size, void* d_ws, size_t ws_size,
                              hipStream_t stream) {
  const float* query = (const float*)d_in[0];
  const float* mem   = (const float*)d_in[1];
  const int*   mask  = (const int*)d_in[2];
  const float* W     = (const float*)d_in[3];
  const float* bias  = (const float*)d_in[4];
  float* out = (float*)d_out;

  char* ws = (char*)d_ws;
  _Float16* qproj  = (_Float16*)ws;                                // 32 MB
  _Float16* memT   = (_Float16*)ws;                                // aliases qproj
  _Float16* queryh = (_Float16*)(ws + (size_t)32 * 1024 * 1024);   // transient
  _Float16* Wh     = (_Float16*)(ws + (size_t)64 * 1024 * 1024);   // transient
  _Float16* wbuf   = (_Float16*)(ws + (size_t)32 * 1024 * 1024);   // 64 MB
  _Float16* memh   = (_Float16*)d_out;                             // 32 MB scratch

  const long LQK = 2048L * 1024, LQM = 2048L * 2048;

  // fp32 -> fp16 pre-passes
  cvt8_kernel<<<dim3(512),  256, 0, stream>>>(W, Wh);
  cvt8_kernel<<<dim3(8192), 256, 0, stream>>>(query, queryh);
  cvt8_kernel<<<dim3(8192), 256, 0, stream>>>(mem, memh);
  // proj: qproj[16384,1024] = queryh * Wh^T + b
  gemm256<_Float16, true><<<dim3(4, 64, 1), 512, 0, stream>>>(
      queryh, Wh, bias, qproj, 16384, 1024, 1024, 0, 0, 0);
  // scores: wbuf[b][2048,2048] = qproj * memh^T
  gemm256<_Float16, false><<<dim3(8, 8, 8), 512, 0, stream>>>(
      qproj, memh, nullptr, wbuf, 2048, 2048, 1024, LQK, LQK, LQM);
  // mask + softmax in place
  softmax_kernel<<<dim3(16384), 256, 0, stream>>>(mask, wbuf);
  // memT[b][1024,2048] = memh^T   (qproj dead -> reuse its space)
  transpose16_kernel<<<dim3(16, 32, 8), 256, 0, stream>>>(memh, memT);
  // pv: out[b][2048,1024] = wbuf * memT^T   (sC = LQK, NOT LQM!)
  gemm256<float, false><<<dim3(4, 8, 8), 512, 0, stream>>>(
      wbuf, memT, nullptr, out, 2048, 1024, 2048, LQM, LQK, LQK);
}

// Round 3
// 508.762 us; speedup vs baseline: 1.2642x; 1.0106x over previous
//
#include <hip/hip_runtime.h>

typedef float    f32x4 __attribute__((ext_vector_type(4)));
typedef _Float16 f16x4 __attribute__((ext_vector_type(4)));
typedef _Float16 f16x8 __attribute__((ext_vector_type(8)));

// direct global->LDS DMA, 16B per lane. LDS dest is wave-uniform base;
// HW writes lane l at (ldsbase + l*16). Global src is per-lane.
__device__ __forceinline__ void gload16(const void* g, void* l) {
  __builtin_amdgcn_global_load_lds(
      (const __attribute__((address_space(1))) void*)g,
      (__attribute__((address_space(3))) void*)l, 16, 0, 0);
}

#define MFMA16(d, a, b) __builtin_amdgcn_mfma_f32_16x16x32_f16(a, b, d, 0, 0, 0)

// ---------------------------------------------------------------------------
// 256x256 deep-pipelined fp16 GEMM, C = A * B^T (+bias), fp32 accum.
// 512 thr = 8 waves (2M x 4N), per-wave C = 128x64, acc[8][4] f32x4.
// BK=64 split as 2 K-halves of 32; LDS = 2 dbuf x {A,B} x 2 K-half x 16KB
// = 128 KiB.  Layout per K-half: [256 rows][32 halfs] (64B rows).
//
// BANK SWIZZLE (round-3 fix): byte col ^= ((row>>1)&3)<<4.  Fragment-read
// bank span = 16*(row&1) + 4*(q ^ ((l15>>1)&3)): the 16 lanes of each
// quarter-wave cover all 8 span-slots x both parities = full 32-bank
// coverage, 2 touches/bank (the ds_read_b128 minimum).  Applied via
// pre-swizzled GLOBAL source (linear DMA dest) + swizzled ds_read col
// (both-sides-or-neither, rule #21).
//
// Schedule per K-tile t (buf d=t&1, staging tile t+1 into d^1), balanced
// 8/4/8/4 ds_reads per phase:
//   p0 (kk0,m0-3): af[0-3]+bf[0-3] | stage A-K0(t+1) | bar | 16 MFMA | bar
//   p1 (kk0,m4-7): af[4-7]         | stage B-K0(t+1) | vmcnt(4) bar | MFMA | bar
//   p2 (kk1,m0-3): af+bf           | stage A-K1(t+1) | bar | MFMA | bar
//   p3 (kk1,m4-7): af              | stage B-K1(t+1) | vmcnt(4) bar | MFMA | bar
// vmcnt(4): the 4 allowed outstanding loads are exactly the two
// not-yet-read half-tiles; loads never drain to 0 in the main loop (T4).
// ---------------------------------------------------------------------------
template <bool STG>
__device__ __forceinline__ void ktile256(
    char* L, int d, size_t go,
    const char* aSrc0, const char* aSrc1,
    const char* bSrc0, const char* bSrc1,
    int ldsStage, int wr, int wc, int l15, int rcb,
    f32x4 (&acc)[8][4]) {
  const char* Ab0 = L + d * 32768;
  const char* Bb0 = L + 65536 + d * 32768;
  const int dn = d ^ 1;
  f16x8 af[4], bf[4];

  // ---- phase 0: kk=0, m 0-3 ----
  #pragma unroll
  for (int m = 0; m < 4; m++)
    af[m] = *(const f16x8*)(Ab0 + (wr + m * 16 + l15) * 64 + rcb);
  #pragma unroll
  for (int n = 0; n < 4; n++)
    bf[n] = *(const f16x8*)(Bb0 + (wc + n * 16 + l15) * 64 + rcb);
  if constexpr (STG) {
    char* dst = L + dn * 32768 + ldsStage;          // A-K0 of t+1
    gload16(aSrc0 + go, dst);
    gload16(aSrc1 + go, dst + 1024);
  }
  __builtin_amdgcn_s_barrier();
  __builtin_amdgcn_s_setprio(1);
  #pragma unroll
  for (int m = 0; m < 4; m++)
    #pragma unroll
    for (int n = 0; n < 4; n++)
      acc[m][n] = MFMA16(acc[m][n], af[m], bf[n]);
  __builtin_amdgcn_s_setprio(0);
  __builtin_amdgcn_s_barrier();

  // ---- phase 1: kk=0, m 4-7 (reuse bf) ----
  #pragma unroll
  for (int m = 0; m < 4; m++)
    af[m] = *(const f16x8*)(Ab0 + (wr + (4 + m) * 16 + l15) * 64 + rcb);
  if constexpr (STG) {
    char* dst = L + 65536 + dn * 32768 + ldsStage;  // B-K0 of t+1
    gload16(bSrc0 + go, dst);
    gload16(bSrc1 + go, dst + 1024);
    asm volatile("s_waitcnt vmcnt(4)" ::: "memory"); // force this tile's K1 landed
  } else {
    asm volatile("s_waitcnt vmcnt(0)" ::: "memory"); // last tile: drain
  }
  __builtin_amdgcn_s_barrier();
  __builtin_amdgcn_s_setprio(1);
  #pragma unroll
  for (int m = 0; m < 4; m++)
    #pragma unroll
    for (int n = 0; n < 4; n++)
      acc[4 + m][n] = MFMA16(acc[4 + m][n], af[m], bf[n]);
  __builtin_amdgcn_s_setprio(0);
  __builtin_amdgcn_s_barrier();

  // ---- phase 2: kk=1, m 0-3 ----
  #pragma unroll
  for (int m = 0; m < 4; m++)
    af[m] = *(const f16x8*)(Ab0 + 16384 + (wr + m * 16 + l15) * 64 + rcb);
  #pragma unroll
  for (int n = 0; n < 4; n++)
    bf[n] = *(const f16x8*)(Bb0 + 16384 + (wc + n * 16 + l15) * 64 + rcb);
  if constexpr (STG) {
    char* dst = L + dn * 32768 + 16384 + ldsStage;  // A-K1 of t+1
    gload16(aSrc0 + go + 64, dst);
    gload16(aSrc1 + go + 64, dst + 1024);
  }
  __builtin_amdgcn_s_barrier();
  __builtin_amdgcn_s_setprio(1);
  #pragma unroll
  for (int m = 0; m < 4; m++)
    #pragma unroll
    for (int n = 0; n < 4; n++)
      acc[m][n] = MFMA16(acc[m][n], af[m], bf[n]);
  __builtin_amdgcn_s_setprio(0);
  __builtin_amdgcn_s_barrier();

  // ---- phase 3: kk=1, m 4-7 ----
  #pragma unroll
  for (int m = 0; m < 4; m++)
    af[m] = *(const f16x8*)(Ab0 + 16384 + (wr + (4 + m) * 16 + l15) * 64 + rcb);
  if constexpr (STG) {
    char* dst = L + 65536 + dn * 32768 + 16384 + ldsStage;  // B-K1 of t+1
    gload16(bSrc0 + go + 64, dst);
    gload16(bSrc1 + go + 64, dst + 1024);
    asm volatile("s_waitcnt vmcnt(4)" ::: "memory"); // force next tile's K0 landed
  }
  __builtin_amdgcn_s_barrier();
  __builtin_amdgcn_s_setprio(1);
  #pragma unroll
  for (int m = 0; m < 4; m++)
    #pragma unroll
    for (int n = 0; n < 4; n++)
      acc[4 + m][n] = MFMA16(acc[4 + m][n], af[m], bf[n]);
  __builtin_amdgcn_s_setprio(0);
  __builtin_amdgcn_s_barrier();
}

template <typename TOUT, bool BIAS>
__global__ __launch_bounds__(512) void gemm256(
    const _Float16* __restrict__ A, const _Float16* __restrict__ B,
    const float* __restrict__ bias, TOUT* __restrict__ Cp,
    int M, int N, int K, long sA, long sB, long sC) {
  __shared__ _Float16 lds[65536];   // 128 KB: A[2][2][256][32] | B[2][2][256][32]
  char* const L = (char*)lds;
  const int tid = threadIdx.x;
  const int w = tid >> 6, l = tid & 63;
  const int l15 = l & 15, q = l >> 4;
  const int wr = (w >> 2) * 128, wc = (w & 3) * 64;
  const int m0 = blockIdx.y * 256, n0 = blockIdx.x * 256;
  const _Float16* Ab = A + (size_t)blockIdx.z * sA;
  const _Float16* Bb = B + (size_t)blockIdx.z * sB;

  // stage addressing: thread covers stored bytes X=(w*2+r)*1024+l*16 of a
  // 16KB K-half; row=X>>6, stored col=(l&3)*16, logical col = stored ^
  // (((row>>1)&3)<<4) = stored ^ ((l>>3)&3)<<4  (lane-constant).
  const int scb = (((l & 3) ^ ((l >> 3) & 3)) << 4);
  const int sr0 = w * 32 + (l >> 2);
  const char* aSrc0 = (const char*)(Ab + (size_t)(m0 + sr0) * K) + scb;
  const char* aSrc1 = (const char*)(Ab + (size_t)(m0 + sr0 + 16) * K) + scb;
  const char* bSrc0 = (const char*)(Bb + (size_t)(n0 + sr0) * K) + scb;
  const char* bSrc1 = (const char*)(Bb + (size_t)(n0 + sr0 + 16) * K) + scb;
  const int ldsStage = w * 2048;              // wave's 2KB within a 16KB half
  // swizzled read col (lane-const): full 32-bank coverage per quarter-wave
  const int rcb = ((q ^ ((l15 >> 1) & 3)) << 4);

  f32x4 acc[8][4] = {};
  const int NT = K >> 6;

  // prologue: stage tile 0 (A-K0, B-K0, A-K1, B-K1) into buf 0
  {
    char* dA = L + ldsStage;
    char* dB = L + 65536 + ldsStage;
    gload16(aSrc0, dA);       gload16(aSrc1, dA + 1024);
    gload16(bSrc0, dB);       gload16(bSrc1, dB + 1024);
    gload16(aSrc0 + 64, dA + 16384); gload16(aSrc1 + 64, dA + 16384 + 1024);
    gload16(bSrc0 + 64, dB + 16384); gload16(bSrc1 + 64, dB + 16384 + 1024);
    asm volatile("s_waitcnt vmcnt(4)" ::: "memory");  // K0 landed, K1 in flight
  }
  __builtin_amdgcn_s_barrier();

  for (int t = 0; t < NT - 1; ++t)
    ktile256<true>(L, t & 1, (size_t)(t + 1) * 128, aSrc0, aSrc1, bSrc0, bSrc1,
                   ldsStage, wr, wc, l15, rcb, acc);
  ktile256<false>(L, (NT - 1) & 1, 0, aSrc0, aSrc1, bSrc0, bSrc1,
                  ldsStage, wr, wc, l15, rcb, acc);

  TOUT* C = Cp + (size_t)blockIdx.z * sC;
  const int q4 = q * 4;
  #pragma unroll
  for (int n = 0; n < 4; n++) {
    int col = n0 + wc + n * 16 + l15;
    float bb = BIAS ? bias[col] : 0.0f;
    #pragma unroll
    for (int m = 0; m < 8; m++) {
      int rowb = m0 + wr + m * 16 + q4;
      #pragma unroll
      for (int rr = 0; rr < 4; rr++)
        C[(size_t)(rowb + rr) * N + col] = (TOUT)(acc[m][n][rr] + bb);
    }
  }
}

// ---------------------------------------------------------------------------
// fp16 transpose: dst[b][d][m] = src[b][m][d].  64x64 tiles, XOR-swizzled
// 8-half groups -> conflict-free both sides.
// ---------------------------------------------------------------------------
__global__ __launch_bounds__(256) void transpose16_kernel(
    const _Float16* __restrict__ src, _Float16* __restrict__ dst) {
  const int Lm = 2048, D = 1024;
  __shared__ _Float16 tile[64 * 64];
  const int d0 = blockIdx.x * 64, m0 = blockIdx.y * 64;
  const _Float16* s = src + (size_t)blockIdx.z * Lm * D;
  _Float16*       d = dst + (size_t)blockIdx.z * D * Lm;
  const int tid = threadIdx.x;
  #pragma unroll
  for (int it = 0; it < 2; it++) {
    int idx = tid + it * 256;
    int mm = idx >> 3, g = idx & 7;
    int pg = g ^ ((mm >> 3) & 7);
    *(f16x8*)&tile[mm * 64 + pg * 8] =
        *(const f16x8*)&s[(size_t)(m0 + mm) * D + d0 + g * 8];
  }
  __syncthreads();
  #pragma unroll
  for (int it = 0; it < 2; it++) {
    int idx = tid + it * 256;
    int dd = idx >> 3, mc = (idx & 7) * 8;
    f16x8 h;
    #pragma unroll
    for (int j = 0; j < 8; j++) {
      int row = mc + j;
      int pg = (dd >> 3) ^ ((row >> 3) & 7);
      h[j] = tile[row * 64 + pg * 8 + (dd & 7)];
    }
    *(f16x8*)&d[(size_t)(d0 + dd) * Lm + m0 + mc] = h;
  }
}

// ---------------------------------------------------------------------------
// per-row mask + softmax in place over fp16 logits; one block per (b,q) row
// ---------------------------------------------------------------------------
__global__ __launch_bounds__(256) void softmax_kernel(
    const int* __restrict__ mask, _Float16* __restrict__ wbuf) {
  const int Lm = 2048;
  size_t row = blockIdx.x;
  _Float16* wr = wbuf + row * Lm;
  const int* mr = mask + row * Lm;
  int tid = threadIdx.x;
  f16x8 lv = *(const f16x8*)&wr[tid * 8];
  int4 ma = *(const int4*)&mr[tid * 8];
  int4 mb = *(const int4*)&mr[tid * 8 + 4];
  int mk[8] = {ma.x, ma.y, ma.z, ma.w, mb.x, mb.y, mb.z, mb.w};
  float v[8];
  float mx = -3.0e38f;
  #pragma unroll
  for (int i = 0; i < 8; i++) {
    float l = (float)lv[i];
    if (mk[i] == 0) l += -1000000.0f;
    v[i] = l;
    mx = fmaxf(mx, l);
  }
  #pragma unroll
  for (int off = 32; off > 0; off >>= 1) mx = fmaxf(mx, __shfl_down(mx, off, 64));
  __shared__ float red[4];
  int wv = tid >> 6;
  if ((tid & 63) == 0) red[wv] = mx;
  __syncthreads();
  mx = fmaxf(fmaxf(red[0], red[1]), fmaxf(red[2], red[3]));
  __syncthreads();
  float s = 0.f;
  #pragma unroll
  for (int i = 0; i < 8; i++) { v[i] = __expf(v[i] - mx); s += v[i]; }
  #pragma unroll
  for (int off = 32; off > 0; off >>= 1) s += __shfl_down(s, off, 64);
  if ((tid & 63) == 0) red[wv] = s;
  __syncthreads();
  float inv = 1.0f / (red[0] + red[1] + red[2] + red[3]);
  f16x8 o;
  #pragma unroll
  for (int i = 0; i < 8; i++) o[i] = (_Float16)(v[i] * inv);
  *(f16x8*)&wr[tid * 8] = o;
}

// ---------------------------------------------------------------------------
// fp32 -> fp16 convert, 8 elems/thread
// ---------------------------------------------------------------------------
__global__ __launch_bounds__(256) void cvt8_kernel(const float* __restrict__ x,
                                                   _Float16* __restrict__ y) {
  size_t i = (size_t)(blockIdx.x * 256 + threadIdx.x) * 8;
  f32x4 a = *(const f32x4*)&x[i];
  f32x4 b = *(const f32x4*)&x[i + 4];
  f16x8 h = {(_Float16)a[0], (_Float16)a[1], (_Float16)a[2], (_Float16)a[3],
             (_Float16)b[0], (_Float16)b[1], (_Float16)b[2], (_Float16)b[3]};
  *(f16x8*)&y[i] = h;
}

// ---------------------------------------------------------------------------
// B=8, Lq=Lm=2048, Din=Dout=1024
//
// buffer plan (ws = 96 MB, d_out = 64 MB used as scratch before pv):
//   ws[0,32M):   qproj fp16 [16384,1024] (proj -> scores);
//                then memT fp16 [B,1024,2048] overwrites it (after scores)
//   ws[32M,64M): queryh fp16 (transient, dead after proj)
//   ws[64M,66M): Wh fp16     (transient, dead after proj)
//   ws[32M,96M): wbuf fp16 [B,Lq,Lm] (scores -> softmax in place -> pv)
//   d_out[0,32M): memh fp16 (cvt of mem; dead before pv writes out)
//
// BUGFIX (kept): pv's output batch stride is LQK (out is [B,2048,1024]).
// ---------------------------------------------------------------------------
extern "C" void kernel_launch(void* const* d_in, const int* in_sizes, int n_in,
                              void* d_out, int out_size, void* d_ws, size_t ws_size,
                              hipStream_t stream) {
  const float* query = (const float*)d_in[0];
  const float* mem   = (const float*)d_in[1];
  const int*   mask  = (const int*)d_in[2];
  const float* W     = (const float*)d_in[3];
  const float* bias  = (const float*)d_in[4];
  float* out = (float*)d_out;

  char* ws = (char*)d_ws;
  _Float16* qproj  = (_Float16*)ws;                                // 32 MB
  _Float16* memT   = (_Float16*)ws;                                // aliases qproj
  _Float16* queryh = (_Float16*)(ws + (size_t)32 * 1024 * 1024);   // transient
  _Float16* Wh     = (_Float16*)(ws + (size_t)64 * 1024 * 1024);   // transient
  _Float16* wbuf   = (_Float16*)(ws + (size_t)32 * 1024 * 1024);   // 64 MB
  _Float16* memh   = (_Float16*)d_out;                             // 32 MB scratch

  const long LQK = 2048L * 1024, LQM = 2048L * 2048;

  // fp32 -> fp16 pre-passes
  cvt8_kernel<<<dim3(512),  256, 0, stream>>>(W, Wh);
  cvt8_kernel<<<dim3(8192), 256, 0, stream>>>(query, queryh);
  cvt8_kernel<<<dim3(8192), 256, 0, stream>>>(mem, memh);
  // proj: qproj[16384,1024] = queryh * Wh^T + b
  gemm256<_Float16, true><<<dim3(4, 64, 1), 512, 0, stream>>>(
      queryh, Wh, bias, qproj, 16384, 1024, 1024, 0, 0, 0);
  // scores: wbuf[b][2048,2048] = qproj * memh^T
  gemm256<_Float16, false><<<dim3(8, 8, 8), 512, 0, stream>>>(
      qproj, memh, nullptr, wbuf, 2048, 2048, 1024, LQK, LQK, LQM);
  // mask + softmax in place
  softmax_kernel<<<dim3(16384), 256, 0, stream>>>(mask, wbuf);
  // memT[b][1024,2048] = memh^T   (qproj dead -> reuse its space)
  transpose16_kernel<<<dim3(16, 32, 8), 256, 0, stream>>>(memh, memT);
  // pv: out[b][2048,1024] = wbuf * memT^T   (sC = LQK, NOT LQM!)
  gemm256<float, false><<<dim3(4, 8, 8), 512, 0, stream>>>(
      wbuf, memT, nullptr, out, 2048, 1024, 2048, LQM, LQK, LQK);
}

// Round 4
// 502.940 us; speedup vs baseline: 1.2788x; 1.0116x over previous
//
#include <hip/hip_runtime.h>

typedef float    f32x4 __attribute__((ext_vector_type(4)));
typedef _Float16 f16x4 __attribute__((ext_vector_type(4)));
typedef _Float16 f16x8 __attribute__((ext_vector_type(8)));

// direct global->LDS DMA, 16B per lane. LDS dest is wave-uniform base;
// HW writes lane l at (ldsbase + l*16). Global src is per-lane.
__device__ __forceinline__ void gload16(const void* g, void* l) {
  __builtin_amdgcn_global_load_lds(
      (const __attribute__((address_space(1))) void*)g,
      (__attribute__((address_space(3))) void*)l, 16, 0, 0);
}

#define MFMA16(d, a, b) __builtin_amdgcn_mfma_f32_16x16x32_f16(a, b, d, 0, 0, 0)

// ---------------------------------------------------------------------------
// 256x256 deep-pipelined fp16 GEMM, C = A * B^T (+bias), fp32 accum.
// 512 thr = 8 waves (2M x 4N), per-wave C = 128x64, acc[8][4] f32x4.
// BK=64 (2 K-halves of 32); LDS = 2 dbuf x {A,B} x 32KB = 128 KiB.
// Layout per K-half: [256 rows][32 halfs] (64B rows).
//
// BANK SWIZZLE (round-3, verified conflicts->0): byte col ^= ((row>>1)&3)<<4,
// applied via pre-swizzled GLOBAL source (linear DMA dest) + swizzled
// ds_read col (both-sides-or-neither, rule #21).
//
// ROUND-4 SCHEDULE: ONE barrier per K-tile, software-pipelined frag reads.
//   tile t body:
//     issue all 8 DMAs for tile t+1 into buf[d^1]   (distance ~ full tile)
//     R0(afX,bfX @kk0: 8 ds) R1(afY @kk0: 4 ds)
//     G0: 16 MFMA (afX,bfX)        | R1 drain overlaps
//     R2(bfY,afX @kk1: 8 ds)       | drains under G1
//     G1: 16 MFMA (afY,bfX)
//     R3(afY @kk1: 4 ds)           | drains under G2
//     G2: 16 MFMA (afX,bfY)
//     G3: 16 MFMA (afY,bfY)
//     vmcnt(0)  <- t+1 DMAs, issued ~3000 cyc ago: near-free
//     s_barrier <- the only barrier
// Compiler inserts counted lgkmcnt before each MFMA group (m97 asm) and
// respects WAR on frag regs (reads re-targeting afX/afY are placed after
// the MFMAs that consume them in program order).
// ---------------------------------------------------------------------------
template <bool STG>
__device__ __forceinline__ void ktile256(
    char* L, int d, size_t go,
    const char* aSrc0, const char* aSrc1,
    const char* bSrc0, const char* bSrc1,
    int ldsStage, int wr, int wc, int l15, int rcb,
    f32x4 (&acc)[8][4]) {
  const char* Ab0 = L + d * 32768;
  const char* Bb0 = L + 65536 + d * 32768;
  const int dn = d ^ 1;

  if constexpr (STG) {                 // stage tile t+1, full BK=64
    char* dA = L + dn * 32768 + ldsStage;
    char* dB = L + 65536 + dn * 32768 + ldsStage;
    gload16(aSrc0 + go, dA);
    gload16(aSrc1 + go, dA + 1024);
    gload16(aSrc0 + go + 64, dA + 16384);
    gload16(aSrc1 + go + 64, dA + 16384 + 1024);
    gload16(bSrc0 + go, dB);
    gload16(bSrc1 + go, dB + 1024);
    gload16(bSrc0 + go + 64, dB + 16384);
    gload16(bSrc1 + go + 64, dB + 16384 + 1024);
  }

  f16x8 afX[4], afY[4], bfX[4], bfY[4];

  // R0: kk0 operands for G0
  #pragma unroll
  for (int m = 0; m < 4; m++)
    afX[m] = *(const f16x8*)(Ab0 + (wr + m * 16 + l15) * 64 + rcb);
  #pragma unroll
  for (int n = 0; n < 4; n++)
    bfX[n] = *(const f16x8*)(Bb0 + (wc + n * 16 + l15) * 64 + rcb);
  // R1: kk0 A-rows 4-7 (drain overlaps G0)
  #pragma unroll
  for (int m = 0; m < 4; m++)
    afY[m] = *(const f16x8*)(Ab0 + (wr + (4 + m) * 16 + l15) * 64 + rcb);

  // G0
  __builtin_amdgcn_s_setprio(1);
  #pragma unroll
  for (int m = 0; m < 4; m++)
    #pragma unroll
    for (int n = 0; n < 4; n++)
      acc[m][n] = MFMA16(acc[m][n], afX[m], bfX[n]);
  __builtin_amdgcn_s_setprio(0);

  // R2: kk1 B + kk1 A-rows 0-3 (afX free after G0 issue; drains under G1)
  #pragma unroll
  for (int n = 0; n < 4; n++)
    bfY[n] = *(const f16x8*)(Bb0 + 16384 + (wc + n * 16 + l15) * 64 + rcb);
  #pragma unroll
  for (int m = 0; m < 4; m++)
    afX[m] = *(const f16x8*)(Ab0 + 16384 + (wr + m * 16 + l15) * 64 + rcb);

  // G1
  __builtin_amdgcn_s_setprio(1);
  #pragma unroll
  for (int m = 0; m < 4; m++)
    #pragma unroll
    for (int n = 0; n < 4; n++)
      acc[4 + m][n] = MFMA16(acc[4 + m][n], afY[m], bfX[n]);
  __builtin_amdgcn_s_setprio(0);

  // R3: kk1 A-rows 4-7 (drains under G2)
  #pragma unroll
  for (int m = 0; m < 4; m++)
    afY[m] = *(const f16x8*)(Ab0 + 16384 + (wr + (4 + m) * 16 + l15) * 64 + rcb);

  // G2
  __builtin_amdgcn_s_setprio(1);
  #pragma unroll
  for (int m = 0; m < 4; m++)
    #pragma unroll
    for (int n = 0; n < 4; n++)
      acc[m][n] = MFMA16(acc[m][n], afX[m], bfY[n]);
  __builtin_amdgcn_s_setprio(0);

  // G3
  __builtin_amdgcn_s_setprio(1);
  #pragma unroll
  for (int m = 0; m < 4; m++)
    #pragma unroll
    for (int n = 0; n < 4; n++)
      acc[4 + m][n] = MFMA16(acc[4 + m][n], afY[m], bfY[n]);
  __builtin_amdgcn_s_setprio(0);

  if constexpr (STG) {
    asm volatile("s_waitcnt vmcnt(0)" ::: "memory");  // t+1 DMAs landed
    __builtin_amdgcn_s_barrier();                     // publish to all waves
  }
}

template <typename TOUT, bool BIAS>
__global__ __launch_bounds__(512) void gemm256(
    const _Float16* __restrict__ A, const _Float16* __restrict__ B,
    const float* __restrict__ bias, TOUT* __restrict__ Cp,
    int M, int N, int K, long sA, long sB, long sC) {
  __shared__ _Float16 lds[65536];   // 128 KB: A[2][2][256][32] | B[2][2][256][32]
  char* const L = (char*)lds;
  const int tid = threadIdx.x;
  const int w = tid >> 6, l = tid & 63;
  const int l15 = l & 15, q = l >> 4;
  const int wr = (w >> 2) * 128, wc = (w & 3) * 64;
  const int m0 = blockIdx.y * 256, n0 = blockIdx.x * 256;
  const _Float16* Ab = A + (size_t)blockIdx.z * sA;
  const _Float16* Bb = B + (size_t)blockIdx.z * sB;

  // stage addressing: thread covers stored bytes X=(w*2+r)*1024+l*16 of a
  // 16KB K-half; row=X>>6, stored col=(l&3)*16, logical col = stored ^
  // (((row>>1)&3)<<4) = stored ^ ((l>>3)&3)<<4  (lane-constant).
  const int scb = (((l & 3) ^ ((l >> 3) & 3)) << 4);
  const int sr0 = w * 32 + (l >> 2);
  const char* aSrc0 = (const char*)(Ab + (size_t)(m0 + sr0) * K) + scb;
  const char* aSrc1 = (const char*)(Ab + (size_t)(m0 + sr0 + 16) * K) + scb;
  const char* bSrc0 = (const char*)(Bb + (size_t)(n0 + sr0) * K) + scb;
  const char* bSrc1 = (const char*)(Bb + (size_t)(n0 + sr0 + 16) * K) + scb;
  const int ldsStage = w * 2048;              // wave's 2KB within a 16KB half
  // swizzled read col (lane-const): full 32-bank coverage per quarter-wave
  const int rcb = ((q ^ ((l15 >> 1) & 3)) << 4);

  f32x4 acc[8][4] = {};
  const int NT = K >> 6;

  // prologue: stage tile 0 into buf 0, full drain once
  {
    char* dA = L + ldsStage;
    char* dB = L + 65536 + ldsStage;
    gload16(aSrc0, dA);       gload16(aSrc1, dA + 1024);
    gload16(aSrc0 + 64, dA + 16384); gload16(aSrc1 + 64, dA + 16384 + 1024);
    gload16(bSrc0, dB);       gload16(bSrc1, dB + 1024);
    gload16(bSrc0 + 64, dB + 16384); gload16(bSrc1 + 64, dB + 16384 + 1024);
    asm volatile("s_waitcnt vmcnt(0)" ::: "memory");
  }
  __builtin_amdgcn_s_barrier();

  for (int t = 0; t < NT - 1; ++t)
    ktile256<true>(L, t & 1, (size_t)(t + 1) * 128, aSrc0, aSrc1, bSrc0, bSrc1,
                   ldsStage, wr, wc, l15, rcb, acc);
  ktile256<false>(L, (NT - 1) & 1, 0, aSrc0, aSrc1, bSrc0, bSrc1,
                  ldsStage, wr, wc, l15, rcb, acc);

  TOUT* C = Cp + (size_t)blockIdx.z * sC;
  const int q4 = q * 4;
  #pragma unroll
  for (int n = 0; n < 4; n++) {
    int col = n0 + wc + n * 16 + l15;
    float bb = BIAS ? bias[col] : 0.0f;
    #pragma unroll
    for (int m = 0; m < 8; m++) {
      int rowb = m0 + wr + m * 16 + q4;
      #pragma unroll
      for (int rr = 0; rr < 4; rr++)
        C[(size_t)(rowb + rr) * N + col] = (TOUT)(acc[m][n][rr] + bb);
    }
  }
}

// ---------------------------------------------------------------------------
// fp16 transpose: dst[b][d][m] = src[b][m][d].  64x64 tiles, XOR-swizzled
// 8-half groups -> conflict-free both sides.
// ---------------------------------------------------------------------------
__global__ __launch_bounds__(256) void transpose16_kernel(
    const _Float16* __restrict__ src, _Float16* __restrict__ dst) {
  const int Lm = 2048, D = 1024;
  __shared__ _Float16 tile[64 * 64];
  const int d0 = blockIdx.x * 64, m0 = blockIdx.y * 64;
  const _Float16* s = src + (size_t)blockIdx.z * Lm * D;
  _Float16*       d = dst + (size_t)blockIdx.z * D * Lm;
  const int tid = threadIdx.x;
  #pragma unroll
  for (int it = 0; it < 2; it++) {
    int idx = tid + it * 256;
    int mm = idx >> 3, g = idx & 7;
    int pg = g ^ ((mm >> 3) & 7);
    *(f16x8*)&tile[mm * 64 + pg * 8] =
        *(const f16x8*)&s[(size_t)(m0 + mm) * D + d0 + g * 8];
  }
  __syncthreads();
  #pragma unroll
  for (int it = 0; it < 2; it++) {
    int idx = tid + it * 256;
    int dd = idx >> 3, mc = (idx & 7) * 8;
    f16x8 h;
    #pragma unroll
    for (int j = 0; j < 8; j++) {
      int row = mc + j;
      int pg = (dd >> 3) ^ ((row >> 3) & 7);
      h[j] = tile[row * 64 + pg * 8 + (dd & 7)];
    }
    *(f16x8*)&d[(size_t)(d0 + dd) * Lm + m0 + mc] = h;
  }
}

// ---------------------------------------------------------------------------
// per-row mask + softmax in place over fp16 logits; one block per (b,q) row
// ---------------------------------------------------------------------------
__global__ __launch_bounds__(256) void softmax_kernel(
    const int* __restrict__ mask, _Float16* __restrict__ wbuf) {
  const int Lm = 2048;
  size_t row = blockIdx.x;
  _Float16* wr = wbuf + row * Lm;
  const int* mr = mask + row * Lm;
  int tid = threadIdx.x;
  f16x8 lv = *(const f16x8*)&wr[tid * 8];
  int4 ma = *(const int4*)&mr[tid * 8];
  int4 mb = *(const int4*)&mr[tid * 8 + 4];
  int mk[8] = {ma.x, ma.y, ma.z, ma.w, mb.x, mb.y, mb.z, mb.w};
  float v[8];
  float mx = -3.0e38f;
  #pragma unroll
  for (int i = 0; i < 8; i++) {
    float l = (float)lv[i];
    if (mk[i] == 0) l += -1000000.0f;
    v[i] = l;
    mx = fmaxf(mx, l);
  }
  #pragma unroll
  for (int off = 32; off > 0; off >>= 1) mx = fmaxf(mx, __shfl_down(mx, off, 64));
  __shared__ float red[4];
  int wv = tid >> 6;
  if ((tid & 63) == 0) red[wv] = mx;
  __syncthreads();
  mx = fmaxf(fmaxf(red[0], red[1]), fmaxf(red[2], red[3]));
  __syncthreads();
  float s = 0.f;
  #pragma unroll
  for (int i = 0; i < 8; i++) { v[i] = __expf(v[i] - mx); s += v[i]; }
  #pragma unroll
  for (int off = 32; off > 0; off >>= 1) s += __shfl_down(s, off, 64);
  if ((tid & 63) == 0) red[wv] = s;
  __syncthreads();
  float inv = 1.0f / (red[0] + red[1] + red[2] + red[3]);
  f16x8 o;
  #pragma unroll
  for (int i = 0; i < 8; i++) o[i] = (_Float16)(v[i] * inv);
  *(f16x8*)&wr[tid * 8] = o;
}

// ---------------------------------------------------------------------------
// fp32 -> fp16 convert, 8 elems/thread
// ---------------------------------------------------------------------------
__global__ __launch_bounds__(256) void cvt8_kernel(const float* __restrict__ x,
                                                   _Float16* __restrict__ y) {
  size_t i = (size_t)(blockIdx.x * 256 + threadIdx.x) * 8;
  f32x4 a = *(const f32x4*)&x[i];
  f32x4 b = *(const f32x4*)&x[i + 4];
  f16x8 h = {(_Float16)a[0], (_Float16)a[1], (_Float16)a[2], (_Float16)a[3],
             (_Float16)b[0], (_Float16)b[1], (_Float16)b[2], (_Float16)b[3]};
  *(f16x8*)&y[i] = h;
}

// ---------------------------------------------------------------------------
// B=8, Lq=Lm=2048, Din=Dout=1024
//
// buffer plan (ws = 96 MB, d_out = 64 MB used as scratch before pv):
//   ws[0,32M):   qproj fp16 [16384,1024] (proj -> scores);
//                then memT fp16 [B,1024,2048] overwrites it (after scores)
//   ws[32M,64M): queryh fp16 (transient, dead after proj)
//   ws[64M,66M): Wh fp16     (transient, dead after proj)
//   ws[32M,96M): wbuf fp16 [B,Lq,Lm] (scores -> softmax in place -> pv)
//   d_out[0,32M): memh fp16 (cvt of mem; dead before pv writes out)
//
// BUGFIX (kept): pv's output batch stride is LQK (out is [B,2048,1024]).
// ---------------------------------------------------------------------------
extern "C" void kernel_launch(void* const* d_in, const int* in_sizes, int n_in,
                              void* d_out, int out_size, void* d_ws, size_t ws_size,
                              hipStream_t stream) {
  const float* query = (const float*)d_in[0];
  const float* mem   = (const float*)d_in[1];
  const int*   mask  = (const int*)d_in[2];
  const float* W     = (const float*)d_in[3];
  const float* bias  = (const float*)d_in[4];
  float* out = (float*)d_out;

  char* ws = (char*)d_ws;
  _Float16* qproj  = (_Float16*)ws;                                // 32 MB
  _Float16* memT   = (_Float16*)ws;                                // aliases qproj
  _Float16* queryh = (_Float16*)(ws + (size_t)32 * 1024 * 1024);   // transient
  _Float16* Wh     = (_Float16*)(ws + (size_t)64 * 1024 * 1024);   // transient
  _Float16* wbuf   = (_Float16*)(ws + (size_t)32 * 1024 * 1024);   // 64 MB
  _Float16* memh   = (_Float16*)d_out;                             // 32 MB scratch

  const long LQK = 2048L * 1024, LQM = 2048L * 2048;

  // fp32 -> fp16 pre-passes
  cvt8_kernel<<<dim3(512),  256, 0, stream>>>(W, Wh);
  cvt8_kernel<<<dim3(8192), 256, 0, stream>>>(query, queryh);
  cvt8_kernel<<<dim3(8192), 256, 0, stream>>>(mem, memh);
  // proj: qproj[16384,1024] = queryh * Wh^T + b
  gemm256<_Float16, true><<<dim3(4, 64, 1), 512, 0, stream>>>(
      queryh, Wh, bias, qproj, 16384, 1024, 1024, 0, 0, 0);
  // scores: wbuf[b][2048,2048] = qproj * memh^T
  gemm256<_Float16, false><<<dim3(8, 8, 8), 512, 0, stream>>>(
      qproj, memh, nullptr, wbuf, 2048, 2048, 1024, LQK, LQK, LQM);
  // mask + softmax in place
  softmax_kernel<<<dim3(16384), 256, 0, stream>>>(mask, wbuf);
  // memT[b][1024,2048] = memh^T   (qproj dead -> reuse its space)
  transpose16_kernel<<<dim3(16, 32, 8), 256, 0, stream>>>(memh, memT);
  // pv: out[b][2048,1024] = wbuf * memT^T   (sC = LQK, NOT LQM!)
  gemm256<float, false><<<dim3(4, 8, 8), 512, 0, stream>>>(
      wbuf, memT, nullptr, out, 2048, 1024, 2048, LQM, LQK, LQK);
}

// Round 5
// 489.055 us; speedup vs baseline: 1.3151x; 1.0284x over previous
//
#include <hip/hip_runtime.h>

typedef float    f32x4 __attribute__((ext_vector_type(4)));
typedef _Float16 f16x4 __attribute__((ext_vector_type(4)));
typedef _Float16 f16x8 __attribute__((ext_vector_type(8)));

// direct global->LDS DMA, 16B per lane. LDS dest is wave-uniform base;
// HW writes lane l at (ldsbase + l*16). Global src is per-lane.
__device__ __forceinline__ void gload16(const void* g, void* l) {
  __builtin_amdgcn_global_load_lds(
      (const __attribute__((address_space(1))) void*)g,
      (__attribute__((address_space(3))) void*)l, 16, 0, 0);
}

#define MFMA16(d, a, b) __builtin_amdgcn_mfma_f32_16x16x32_f16(a, b, d, 0, 0, 0)

// ---------------------------------------------------------------------------
// 256x256 deep-pipelined fp16 GEMM, C = A * B^T (+bias), fp32 accum.
// 512 thr = 8 waves (2M x 4N), per-wave C = 128x64, acc[8][4] f32x4.
// BK=64 (2 K-halves of 32); LDS = 2 dbuf x {A,B} x 32KB = 128 KiB.
// Layout per K-half: [256 rows][32 halfs] (64B rows).
//
// BANK SWIZZLE (round-3, verified conflicts->0): byte col ^= ((row>>1)&3)<<4,
// applied via pre-swizzled GLOBAL source (linear DMA dest) + swizzled
// ds_read col (both-sides-or-neither, rule #21).
//
// ROUND-5: XCD-clustered block remap (T1). lin = hw-linearized blockIdx;
// l = (lin&7)*(nwg/8) + (lin>>3) gives each XCD one CONTIGUOUS chunk of
// logical blocks (bijective when nwg%8==0 -- all our grids are). Decompose
// l x-innermost: for scores/pv each XCD owns exactly one batch -> its
// B-panels (4MB) sit resident in that XCD's L2, A-panels are reused by
// consecutive blocks. Turns cross-XCD HBM re-fetch (FETCH=144MB on a 64MB
// footprint) into same-XCD L2 hits.
//
// Schedule (round-4): ONE barrier per K-tile, software-pipelined frag reads.
// ---------------------------------------------------------------------------
template <bool STG>
__device__ __forceinline__ void ktile256(
    char* L, int d, size_t go,
    const char* aSrc0, const char* aSrc1,
    const char* bSrc0, const char* bSrc1,
    int ldsStage, int wr, int wc, int l15, int rcb,
    f32x4 (&acc)[8][4]) {
  const char* Ab0 = L + d * 32768;
  const char* Bb0 = L + 65536 + d * 32768;
  const int dn = d ^ 1;

  if constexpr (STG) {                 // stage tile t+1, full BK=64
    char* dA = L + dn * 32768 + ldsStage;
    char* dB = L + 65536 + dn * 32768 + ldsStage;
    gload16(aSrc0 + go, dA);
    gload16(aSrc1 + go, dA + 1024);
    gload16(aSrc0 + go + 64, dA + 16384);
    gload16(aSrc1 + go + 64, dA + 16384 + 1024);
    gload16(bSrc0 + go, dB);
    gload16(bSrc1 + go, dB + 1024);
    gload16(bSrc0 + go + 64, dB + 16384);
    gload16(bSrc1 + go + 64, dB + 16384 + 1024);
  }

  f16x8 afX[4], afY[4], bfX[4], bfY[4];

  // R0: kk0 operands for G0
  #pragma unroll
  for (int m = 0; m < 4; m++)
    afX[m] = *(const f16x8*)(Ab0 + (wr + m * 16 + l15) * 64 + rcb);
  #pragma unroll
  for (int n = 0; n < 4; n++)
    bfX[n] = *(const f16x8*)(Bb0 + (wc + n * 16 + l15) * 64 + rcb);
  // R1: kk0 A-rows 4-7 (drain overlaps G0)
  #pragma unroll
  for (int m = 0; m < 4; m++)
    afY[m] = *(const f16x8*)(Ab0 + (wr + (4 + m) * 16 + l15) * 64 + rcb);

  // G0
  __builtin_amdgcn_s_setprio(1);
  #pragma unroll
  for (int m = 0; m < 4; m++)
    #pragma unroll
    for (int n = 0; n < 4; n++)
      acc[m][n] = MFMA16(acc[m][n], afX[m], bfX[n]);
  __builtin_amdgcn_s_setprio(0);

  // R2: kk1 B + kk1 A-rows 0-3 (drains under G1)
  #pragma unroll
  for (int n = 0; n < 4; n++)
    bfY[n] = *(const f16x8*)(Bb0 + 16384 + (wc + n * 16 + l15) * 64 + rcb);
  #pragma unroll
  for (int m = 0; m < 4; m++)
    afX[m] = *(const f16x8*)(Ab0 + 16384 + (wr + m * 16 + l15) * 64 + rcb);

  // G1
  __builtin_amdgcn_s_setprio(1);
  #pragma unroll
  for (int m = 0; m < 4; m++)
    #pragma unroll
    for (int n = 0; n < 4; n++)
      acc[4 + m][n] = MFMA16(acc[4 + m][n], afY[m], bfX[n]);
  __builtin_amdgcn_s_setprio(0);

  // R3: kk1 A-rows 4-7 (drains under G2)
  #pragma unroll
  for (int m = 0; m < 4; m++)
    afY[m] = *(const f16x8*)(Ab0 + 16384 + (wr + (4 + m) * 16 + l15) * 64 + rcb);

  // G2
  __builtin_amdgcn_s_setprio(1);
  #pragma unroll
  for (int m = 0; m < 4; m++)
    #pragma unroll
    for (int n = 0; n < 4; n++)
      acc[m][n] = MFMA16(acc[m][n], afX[m], bfY[n]);
  __builtin_amdgcn_s_setprio(0);

  // G3
  __builtin_amdgcn_s_setprio(1);
  #pragma unroll
  for (int m = 0; m < 4; m++)
    #pragma unroll
    for (int n = 0; n < 4; n++)
      acc[4 + m][n] = MFMA16(acc[4 + m][n], afY[m], bfY[n]);
  __builtin_amdgcn_s_setprio(0);

  if constexpr (STG) {
    asm volatile("s_waitcnt vmcnt(0)" ::: "memory");  // t+1 DMAs landed
    __builtin_amdgcn_s_barrier();                     // publish to all waves
  }
}

template <typename TOUT, bool BIAS>
__global__ __launch_bounds__(512) void gemm256(
    const _Float16* __restrict__ A, const _Float16* __restrict__ B,
    const float* __restrict__ bias, TOUT* __restrict__ Cp,
    int M, int N, int K, long sA, long sB, long sC) {
  __shared__ _Float16 lds[65536];   // 128 KB: A[2][2][256][32] | B[2][2][256][32]
  char* const L = (char*)lds;
  const int tid = threadIdx.x;
  const int w = tid >> 6, l = tid & 63;
  const int l15 = l & 15, q = l >> 4;
  const int wr = (w >> 2) * 128, wc = (w & 3) * 64;

  // ---- XCD-clustered bijective block remap (T1) ----
  const int gx = gridDim.x, gy = gridDim.y;
  const int nwg = gx * gy * gridDim.z;
  const int lin = (blockIdx.z * gy + blockIdx.y) * gx + blockIdx.x;
  const int li = (lin & 7) * (nwg >> 3) + (lin >> 3);
  const int bx = li % gx;
  const int t1 = li / gx;
  const int by = t1 % gy;
  const int bz = t1 / gy;

  const int m0 = by * 256, n0 = bx * 256;
  const _Float16* Ab = A + (size_t)bz * sA;
  const _Float16* Bb = B + (size_t)bz * sB;

  // stage addressing: thread covers stored bytes X=(w*2+r)*1024+l*16 of a
  // 16KB K-half; row=X>>6, stored col=(l&3)*16, logical col = stored ^
  // (((row>>1)&3)<<4) = stored ^ ((l>>3)&3)<<4  (lane-constant).
  const int scb = (((l & 3) ^ ((l >> 3) & 3)) << 4);
  const int sr0 = w * 32 + (l >> 2);
  const char* aSrc0 = (const char*)(Ab + (size_t)(m0 + sr0) * K) + scb;
  const char* aSrc1 = (const char*)(Ab + (size_t)(m0 + sr0 + 16) * K) + scb;
  const char* bSrc0 = (const char*)(Bb + (size_t)(n0 + sr0) * K) + scb;
  const char* bSrc1 = (const char*)(Bb + (size_t)(n0 + sr0 + 16) * K) + scb;
  const int ldsStage = w * 2048;              // wave's 2KB within a 16KB half
  // swizzled read col (lane-const): full 32-bank coverage per quarter-wave
  const int rcb = ((q ^ ((l15 >> 1) & 3)) << 4);

  f32x4 acc[8][4] = {};
  const int NT = K >> 6;

  // prologue: stage tile 0 into buf 0, full drain once
  {
    char* dA = L + ldsStage;
    char* dB = L + 65536 + ldsStage;
    gload16(aSrc0, dA);       gload16(aSrc1, dA + 1024);
    gload16(aSrc0 + 64, dA + 16384); gload16(aSrc1 + 64, dA + 16384 + 1024);
    gload16(bSrc0, dB);       gload16(bSrc1, dB + 1024);
    gload16(bSrc0 + 64, dB + 16384); gload16(bSrc1 + 64, dB + 16384 + 1024);
    asm volatile("s_waitcnt vmcnt(0)" ::: "memory");
  }
  __builtin_amdgcn_s_barrier();

  for (int t = 0; t < NT - 1; ++t)
    ktile256<true>(L, t & 1, (size_t)(t + 1) * 128, aSrc0, aSrc1, bSrc0, bSrc1,
                   ldsStage, wr, wc, l15, rcb, acc);
  ktile256<false>(L, (NT - 1) & 1, 0, aSrc0, aSrc1, bSrc0, bSrc1,
                  ldsStage, wr, wc, l15, rcb, acc);

  TOUT* C = Cp + (size_t)bz * sC;
  const int q4 = q * 4;
  #pragma unroll
  for (int n = 0; n < 4; n++) {
    int col = n0 + wc + n * 16 + l15;
    float bb = BIAS ? bias[col] : 0.0f;
    #pragma unroll
    for (int m = 0; m < 8; m++) {
      int rowb = m0 + wr + m * 16 + q4;
      #pragma unroll
      for (int rr = 0; rr < 4; rr++)
        C[(size_t)(rowb + rr) * N + col] = (TOUT)(acc[m][n][rr] + bb);
    }
  }
}

// ---------------------------------------------------------------------------
// fp16 transpose: dst[b][d][m] = src[b][m][d].  64x64 tiles, XOR-swizzled
// 8-half groups -> conflict-free both sides.
// ---------------------------------------------------------------------------
__global__ __launch_bounds__(256) void transpose16_kernel(
    const _Float16* __restrict__ src, _Float16* __restrict__ dst) {
  const int Lm = 2048, D = 1024;
  __shared__ _Float16 tile[64 * 64];
  const int d0 = blockIdx.x * 64, m0 = blockIdx.y * 64;
  const _Float16* s = src + (size_t)blockIdx.z * Lm * D;
  _Float16*       d = dst + (size_t)blockIdx.z * D * Lm;
  const int tid = threadIdx.x;
  #pragma unroll
  for (int it = 0; it < 2; it++) {
    int idx = tid + it * 256;
    int mm = idx >> 3, g = idx & 7;
    int pg = g ^ ((mm >> 3) & 7);
    *(f16x8*)&tile[mm * 64 + pg * 8] =
        *(const f16x8*)&s[(size_t)(m0 + mm) * D + d0 + g * 8];
  }
  __syncthreads();
  #pragma unroll
  for (int it = 0; it < 2; it++) {
    int idx = tid + it * 256;
    int dd = idx >> 3, mc = (idx & 7) * 8;
    f16x8 h;
    #pragma unroll
    for (int j = 0; j < 8; j++) {
      int row = mc + j;
      int pg = (dd >> 3) ^ ((row >> 3) & 7);
      h[j] = tile[row * 64 + pg * 8 + (dd & 7)];
    }
    *(f16x8*)&d[(size_t)(d0 + dd) * Lm + m0 + mc] = h;
  }
}

// ---------------------------------------------------------------------------
// per-row mask + softmax in place over fp16 logits; one block per (b,q) row
// ---------------------------------------------------------------------------
__global__ __launch_bounds__(256) void softmax_kernel(
    const int* __restrict__ mask, _Float16* __restrict__ wbuf) {
  const int Lm = 2048;
  size_t row = blockIdx.x;
  _Float16* wr = wbuf + row * Lm;
  const int* mr = mask + row * Lm;
  int tid = threadIdx.x;
  f16x8 lv = *(const f16x8*)&wr[tid * 8];
  int4 ma = *(const int4*)&mr[tid * 8];
  int4 mb = *(const int4*)&mr[tid * 8 + 4];
  int mk[8] = {ma.x, ma.y, ma.z, ma.w, mb.x, mb.y, mb.z, mb.w};
  float v[8];
  float mx = -3.0e38f;
  #pragma unroll
  for (int i = 0; i < 8; i++) {
    float l = (float)lv[i];
    if (mk[i] == 0) l += -1000000.0f;
    v[i] = l;
    mx = fmaxf(mx, l);
  }
  #pragma unroll
  for (int off = 32; off > 0; off >>= 1) mx = fmaxf(mx, __shfl_down(mx, off, 64));
  __shared__ float red[4];
  int wv = tid >> 6;
  if ((tid & 63) == 0) red[wv] = mx;
  __syncthreads();
  mx = fmaxf(fmaxf(red[0], red[1]), fmaxf(red[2], red[3]));
  __syncthreads();
  float s = 0.f;
  #pragma unroll
  for (int i = 0; i < 8; i++) { v[i] = __expf(v[i] - mx); s += v[i]; }
  #pragma unroll
  for (int off = 32; off > 0; off >>= 1) s += __shfl_down(s, off, 64);
  if ((tid & 63) == 0) red[wv] = s;
  __syncthreads();
  float inv = 1.0f / (red[0] + red[1] + red[2] + red[3]);
  f16x8 o;
  #pragma unroll
  for (int i = 0; i < 8; i++) o[i] = (_Float16)(v[i] * inv);
  *(f16x8*)&wr[tid * 8] = o;
}

// ---------------------------------------------------------------------------
// fp32 -> fp16 convert, 8 elems/thread
// ---------------------------------------------------------------------------
__global__ __launch_bounds__(256) void cvt8_kernel(const float* __restrict__ x,
                                                   _Float16* __restrict__ y) {
  size_t i = (size_t)(blockIdx.x * 256 + threadIdx.x) * 8;
  f32x4 a = *(const f32x4*)&x[i];
  f32x4 b = *(const f32x4*)&x[i + 4];
  f16x8 h = {(_Float16)a[0], (_Float16)a[1], (_Float16)a[2], (_Float16)a[3],
             (_Float16)b[0], (_Float16)b[1], (_Float16)b[2], (_Float16)b[3]};
  *(f16x8*)&y[i] = h;
}

// ---------------------------------------------------------------------------
// B=8, Lq=Lm=2048, Din=Dout=1024
//
// buffer plan (ws = 96 MB, d_out = 64 MB used as scratch before pv):
//   ws[0,32M):   qproj fp16 [16384,1024] (proj -> scores);
//                then memT fp16 [B,1024,2048] overwrites it (after scores)
//   ws[32M,64M): queryh fp16 (transient, dead after proj)
//   ws[64M,66M): Wh fp16     (transient, dead after proj)
//   ws[32M,96M): wbuf fp16 [B,Lq,Lm] (scores -> softmax in place -> pv)
//   d_out[0,32M): memh fp16 (cvt of mem; dead before pv writes out)
//
// BUGFIX (kept): pv's output batch stride is LQK (out is [B,2048,1024]).
// ---------------------------------------------------------------------------
extern "C" void kernel_launch(void* const* d_in, const int* in_sizes, int n_in,
                              void* d_out, int out_size, void* d_ws, size_t ws_size,
                              hipStream_t stream) {
  const float* query = (const float*)d_in[0];
  const float* mem   = (const float*)d_in[1];
  const int*   mask  = (const int*)d_in[2];
  const float* W     = (const float*)d_in[3];
  const float* bias  = (const float*)d_in[4];
  float* out = (float*)d_out;

  char* ws = (char*)d_ws;
  _Float16* qproj  = (_Float16*)ws;                                // 32 MB
  _Float16* memT   = (_Float16*)ws;                                // aliases qproj
  _Float16* queryh = (_Float16*)(ws + (size_t)32 * 1024 * 1024);   // transient
  _Float16* Wh     = (_Float16*)(ws + (size_t)64 * 1024 * 1024);   // transient
  _Float16* wbuf   = (_Float16*)(ws + (size_t)32 * 1024 * 1024);   // 64 MB
  _Float16* memh   = (_Float16*)d_out;                             // 32 MB scratch

  const long LQK = 2048L * 1024, LQM = 2048L * 2048;

  // fp32 -> fp16 pre-passes
  cvt8_kernel<<<dim3(512),  256, 0, stream>>>(W, Wh);
  cvt8_kernel<<<dim3(8192), 256, 0, stream>>>(query, queryh);
  cvt8_kernel<<<dim3(8192), 256, 0, stream>>>(mem, memh);
  // proj: qproj[16384,1024] = queryh * Wh^T + b  (nwg=256, %8==0)
  gemm256<_Float16, true><<<dim3(4, 64, 1), 512, 0, stream>>>(
      queryh, Wh, bias, qproj, 16384, 1024, 1024, 0, 0, 0);
  // scores: wbuf[b][2048,2048] = qproj * memh^T  (nwg=512: 1 batch per XCD)
  gemm256<_Float16, false><<<dim3(8, 8, 8), 512, 0, stream>>>(
      qproj, memh, nullptr, wbuf, 2048, 2048, 1024, LQK, LQK, LQM);
  // mask + softmax in place
  softmax_kernel<<<dim3(16384), 256, 0, stream>>>(mask, wbuf);
  // memT[b][1024,2048] = memh^T   (qproj dead -> reuse its space)
  transpose16_kernel<<<dim3(16, 32, 8), 256, 0, stream>>>(memh, memT);
  // pv: out[b][2048,1024] = wbuf * memT^T  (nwg=256: 1 batch per XCD; sC=LQK)
  gemm256<float, false><<<dim3(4, 8, 8), 512, 0, stream>>>(
      wbuf, memT, nullptr, out, 2048, 1024, 2048, LQM, LQK, LQK);
}